// Round 14
// baseline (1944.716 us; speedup 1.0000x reference)
//
#include <hip/hip_runtime.h>

// Problem constants
#define NTOK 65536          // B*S tokens
#define DDIM 64             // embedding dim
#define KCB  4096           // codebook size
#define MB   64             // tokens per block
#define NTILES 256          // 16-col tiles in codebook
#define TPW  128            // tiles per wave (half codebook; 2 waves share a half)
#define LCAP 4096           // candidate capacity (~1300/block; exhaustive fallback on overflow)
#define FCAP 16             // per-lane FIFO entries (expect ~5; 17th valid hit -> poison -> fallback)
#define WWIN 5.0e-4f        // >= 2*delta; delta <= 2.2e-4 (single-product worst case)
#define IDXOFF  (NTOK * DDIM)
#define LOSSOFF (NTOK * DDIM + NTOK)
#define ZPAD 68             // LDS row stride (floats): 272B, 16B-aligned, breaks banks

typedef __bf16 bf16x8 __attribute__((ext_vector_type(8)));
typedef float  f32x4  __attribute__((ext_vector_type(4)));

__device__ __forceinline__ float opaque(float x) { asm volatile("" : "+v"(x)); return x; }

// numpy pairwise sum of squares, n=64
__device__ __forceinline__ float np_sumsq64(const float* __restrict__ v) {
    float r[8];
#pragma unroll
    for (int j = 0; j < 8; ++j) r[j] = opaque(v[j] * v[j]);
#pragma unroll
    for (int i = 1; i < 8; ++i)
#pragma unroll
        for (int j = 0; j < 8; ++j) r[j] += opaque(v[8 * i + j] * v[8 * i + j]);
    return ((r[0] + r[1]) + (r[2] + r[3])) + ((r[4] + r[5]) + (r[6] + r[7]));
}

__device__ __forceinline__ unsigned short bf16rne(float x) {
    unsigned u = __float_as_uint(x);
    return (unsigned short)((u + 0x7fffu + ((u >> 16) & 1u)) >> 16);
}

// ---- Prep: exact e2 (np pairwise) + fragment-packed bf16(high) codebook ----
// pfh[tile*128 + kh*64 + lane]: lane = quad*16+l15 holds
//   bf16(e_row[tile*16+l15][quad*8 + kh*32 .. +8])  (16 B = 8 bf16)
__global__ void k_prep(const float* __restrict__ emb, float* __restrict__ e2,
                       uint4* __restrict__ pfh, double* __restrict__ lossacc,
                       unsigned* __restrict__ donecnt) {
    int k = blockIdx.x * blockDim.x + threadIdx.x;
    if (k == 0) { *lossacc = 0.0; *donecnt = 0u; }
    if (k >= KCB) return;
    float row[DDIM];
    const float4* r4 = (const float4*)(emb + (size_t)k * DDIM);
#pragma unroll
    for (int i = 0; i < DDIM / 4; ++i) {
        float4 v = r4[i];
        row[4*i+0] = v.x; row[4*i+1] = v.y; row[4*i+2] = v.z; row[4*i+3] = v.w;
    }
    e2[k] = np_sumsq64(row);
    const int tile = k >> 4, rr = k & 15;
#pragma unroll
    for (int q = 0; q < 4; ++q) {
#pragma unroll
        for (int kh = 0; kh < 2; ++kh) {
            union { uint4 v; unsigned short s[8]; } th;
#pragma unroll
            for (int j = 0; j < 8; ++j) th.s[j] = bf16rne(row[q*8 + kh*32 + j]);
            pfh[(size_t)tile * 128 + kh * 64 + q * 16 + rr] = th.v;
        }
    }
}

// ---- Main: R8 structure + FIFO capture (trash-slot fixed) + fused finalize --
// Shape r0-r12-proven optimum: 256 thr / 4 waves, wave (g,hh) = 32 tokens x
// half codebook, VGPR<=64; density beats occupancy (r12).
// Capture: per-lane LDS FIFO replaces the in-sweep per-hit atomicAdd (which
// was a dependent ~120cyc LDS RMW on the critical path + same-address
// contention). Push = one fire-and-forget ds_write + branch-free count bump.
// R13 BUG FIXED: pushes at cnt>=FCAP now land in a TRASH SLOT (index FCAP,
// never read) instead of clobbering slot FCAP-1; a 17th VALID hit advances
// cnt past FCAP -> poison -> exhaustive fallback. Invariant: slots
// [0, min(cnt,FCAP)) are exactly the valid captures.
// Flush: ONE prefix-atomicAdd per lane, batched decode -> list. Same
// predicate as R8 -> identical candidate set.
// k_fin folded in via device-scope done-counter (saves a launch + gap).
// thr FIXED after 512-code preview seed. Exact rescore from LDS z:
// s = fl(fl(z2+e2)-seqFMA(2z*e)) -> lex (s,n).
__global__ __launch_bounds__(256, 4)
void k_vq(const float* __restrict__ z, const float* __restrict__ emb,
          const float* __restrict__ e2g, const uint4* __restrict__ pfh,
          float* __restrict__ out, double* __restrict__ lossacc,
          unsigned* __restrict__ donecnt) {
    __shared__ float z2s[MB];
    __shared__ unsigned v0u[MB];
    __shared__ unsigned long long keys[MB];
    __shared__ unsigned list[LCAP];              // 16 KB; reused as red[] after rescore
    __shared__ unsigned fifo[(FCAP + 1) * 4 * 64]; // 17.4 KB FIFO + trash slot
    __shared__ int lcnt;
    __shared__ int bidx_s[MB];
    __shared__ float zrow_s[MB][ZPAD];           // 17 KB staged z block

    const int tid  = threadIdx.x;
    const int lane = tid & 63;
    const int l15  = lane & 15;
    const int quad = lane >> 4;
    const int wn   = tid >> 6;
    const int g    = wn >> 1;    // token half: tokens [g*32, g*32+32)
    const int hh   = wn & 1;     // tile half: tiles [hh*128, hh*128+128)
    const int tok0 = blockIdx.x * MB;
    const size_t zbase = (size_t)tok0 * DDIM;

    if (tid < MB) { v0u[tid] = 0x7f800000u; keys[tid] = 0xFFFFFFFFFFFFFFFFull; }
    if (tid == 0) lcnt = 0;

    // ---- A-fragments: bf16(-2z) for this wave's 32 tokens — 16 VGPRs ----
    bf16x8 Ah[2][2];   // [ms_local][kh]
#pragma unroll
    for (int ms = 0; ms < 2; ++ms) {
        const float* p = z + zbase + (size_t)((2 * g + ms) * 16 + l15) * DDIM + quad * 8;
#pragma unroll
        for (int kh = 0; kh < 2; ++kh) {
            float4 u0 = *(const float4*)(p + kh * 32);
            float4 u1 = *(const float4*)(p + kh * 32 + 4);
            float d[8] = {-(u0.x + u0.x), -(u0.y + u0.y), -(u0.z + u0.z), -(u0.w + u0.w),
                          -(u1.x + u1.x), -(u1.y + u1.y), -(u1.z + u1.z), -(u1.w + u1.w)};
            union { bf16x8 v; unsigned short u[8]; } th;
#pragma unroll
            for (int j = 0; j < 8; ++j) th.u[j] = bf16rne(d[j]);
            Ah[ms][kh] = th.v;
        }
    }

    // ---- Stage z block -> LDS (coalesced float4; rows padded to 68) ----
#pragma unroll
    for (int it = 0; it < 4; ++it) {
        int f = it * 256 + tid;              // 0..1023 float4 slots
        int tt = f >> 4, cc = f & 15;
        float4 v = ((const float4*)(z + zbase))[f];
        *(float4*)&zrow_s[tt][cc * 4] = v;
    }
    __syncthreads();   // zrow_s ready (also covers v0u/keys/lcnt init)

    // z2 per token (exact np pairwise) from LDS
    if (tid < MB) {
        float row[DDIM];
#pragma unroll
        for (int i = 0; i < DDIM / 4; ++i) {
            float4 v = *(const float4*)&zrow_s[tid][i * 4];
            row[4*i+0] = v.x; row[4*i+1] = v.y; row[4*i+2] = v.z; row[4*i+3] = v.w;
        }
        z2s[tid] = np_sumsq64(row);
    }

    const uint4* pbase = pfh + (size_t)hh * 128 * 128 + lane;

    // ---- preview (16 tiles/wave; 2 waves/token-half -> 512-code seed) ----
    float rm[8];
#pragma unroll
    for (int i = 0; i < 8; ++i) rm[i] = 3.0e38f;
#pragma unroll 1
    for (int t = 0; t < 16; ++t) {
        union { uint4 q; bf16x8 v; } b0, b1;
        b0.q = pbase[(size_t)t * 128]; b1.q = pbase[(size_t)t * 128 + 64];
#pragma unroll
        for (int ms = 0; ms < 2; ++ms) {
            f32x4 a = {0.5f, 0.5f, 0.5f, 0.5f};
            a = __builtin_amdgcn_mfma_f32_16x16x32_bf16(Ah[ms][0], b0.v, a, 0, 0, 0);
            a = __builtin_amdgcn_mfma_f32_16x16x32_bf16(Ah[ms][1], b1.v, a, 0, 0, 0);
#pragma unroll
            for (int r = 0; r < 4; ++r) rm[ms*4+r] = fminf(rm[ms*4+r], a[r]);
        }
    }
    // commit raw mins (16-lane group reduce -> block atomicMin)
#pragma unroll
    for (int i = 0; i < 8; ++i) {
        float v = rm[i];
        v = fminf(v, __shfl_xor(v, 1));
        v = fminf(v, __shfl_xor(v, 2));
        v = fminf(v, __shfl_xor(v, 4));
        v = fminf(v, __shfl_xor(v, 8));
        if (l15 == 0)
            atomicMin(&v0u[(2*g + (i>>2)) * 16 + quad*4 + (i&3)], __float_as_uint(v));
    }
    __syncthreads();   // v0u complete block-wide

    float thr[8];      // FIXED for the whole sweep: block 512-code min + W
#pragma unroll
    for (int i = 0; i < 8; ++i)
        thr[i] = __uint_as_float(v0u[(2*g + (i>>2)) * 16 + quad*4 + (i&3)]) + WWIN;

    // ---- main sweep: R8 skeleton; capture -> per-lane FIFO (no atomics) ----
    int cnt = 0;                              // per-lane valid-entry count
    const int fl = wn * 64 + lane;            // FIFO column for this thread
    auto sweep_pair = [&](uint4 p0, uint4 p1, uint4 q0, uint4 q1, int t) {
        unsigned m80 = 0, m81 = 0;
        {
            union { uint4 q; bf16x8 v; } b0u, b1u;
            b0u.q = p0; b1u.q = p1;
#pragma unroll
            for (int ms = 0; ms < 2; ++ms) {
                f32x4 a = {0.5f, 0.5f, 0.5f, 0.5f};
                a = __builtin_amdgcn_mfma_f32_16x16x32_bf16(Ah[ms][0], b0u.v, a, 0, 0, 0);
                a = __builtin_amdgcn_mfma_f32_16x16x32_bf16(Ah[ms][1], b1u.v, a, 0, 0, 0);
#pragma unroll
                for (int r = 0; r < 4; ++r)
                    m80 |= (a[r] <= thr[ms*4+r]) ? (1u << (ms*4+r)) : 0u;
            }
        }
        {
            union { uint4 q; bf16x8 v; } b0u, b1u;
            b0u.q = q0; b1u.q = q1;
#pragma unroll
            for (int ms = 0; ms < 2; ++ms) {
                f32x4 a = {0.5f, 0.5f, 0.5f, 0.5f};
                a = __builtin_amdgcn_mfma_f32_16x16x32_bf16(Ah[ms][0], b0u.v, a, 0, 0, 0);
                a = __builtin_amdgcn_mfma_f32_16x16x32_bf16(Ah[ms][1], b1u.v, a, 0, 0, 0);
#pragma unroll
                for (int r = 0; r < 4; ++r)
                    m81 |= (a[r] <= thr[ms*4+r]) ? (1u << (ms*4+r)) : 0u;
            }
        }
        // branch-free push; writes at cnt>=FCAP go to the trash slot (FCAP),
        // which is never read — valid slots [0,FCAP) are never clobbered.
        int s0 = cnt < FCAP ? cnt : FCAP;
        fifo[s0 * 256 + fl] = ((unsigned)t << 8) | m80;
        cnt += (m80 != 0u);
        int s1 = cnt < FCAP ? cnt : FCAP;
        fifo[s1 * 256 + fl] = ((unsigned)(t + 1) << 8) | m81;
        cnt += (m81 != 0u);
    };

    uint4 a0 = pbase[0],   a1 = pbase[64];
    uint4 b0 = pbase[128], b1 = pbase[192];
    const uint4* pf = pbase + 256;
#pragma unroll 1
    for (int t = 0; t < TPW; t += 2) {
        uint4 c0 = a0, c1 = a1, d0 = b0, d1 = b1;
        if (t + 2 < TPW) {
            c0 = pf[0]; c1 = pf[64]; d0 = pf[128]; d1 = pf[192];
            pf += 256;
        }
        sweep_pair(a0, a1, b0, b1, t);
        a0 = c0; a1 = c1; b0 = d0; b1 = d1;
    }

    // ---- flush: one prefix-atomicAdd per lane, batched decode -> list ----
    {
        int ne = cnt < FCAP ? cnt : FCAP;
        int tot = 0;
        for (int e = 0; e < ne; ++e)
            tot += __popc(fifo[e * 256 + fl] & 255u);
        int myadd = (cnt > FCAP) ? (LCAP + 1) : tot;   // overflow poison -> fallback
        int base = 0;
        if (myadd) base = atomicAdd(&lcnt, myadd);
        for (int e = 0; e < ne; ++e) {
            unsigned w = fifo[e * 256 + fl];
            unsigned m8 = w & 255u;
            int tt = (int)(w >> 8);
            while (m8) {
                int b = __builtin_ctz(m8);
                m8 &= m8 - 1;
                int m    = (2 * g + (b >> 2)) * 16 + quad * 4 + (b & 3);
                int ncol = hh * 2048 + tt * 16 + l15;
                if (base < LCAP)
                    list[base] = ((unsigned)m << 12) | (unsigned)ncol;
                ++base;
            }
        }
    }
    __syncthreads();   // list complete & visible

    // ---- Exact rescore (np chain), lexicographic (s, n) min per token ----
    int cnt2 = lcnt;
    if (cnt2 <= LCAP) {
        for (int i = tid; i < cnt2; i += 256) {
            unsigned e = list[i];
            int m = (int)(e >> 12), n = (int)(e & 4095u);
            const float4* er4 = (const float4*)(emb + (size_t)n * DDIM);
            const float4* zr4 = (const float4*)&zrow_s[m][0];
            float a = 0.f;
#pragma unroll
            for (int j4 = 0; j4 < 16; ++j4) {
                float4 ev = er4[j4];
                float4 zv = zr4[j4];
                a = fmaf(zv.x + zv.x, ev.x, a);
                a = fmaf(zv.y + zv.y, ev.y, a);
                a = fmaf(zv.z + zv.z, ev.z, a);
                a = fmaf(zv.w + zv.w, ev.w, a);
            }
            float s = (z2s[m] + e2g[n]) - a;   // two fp32 roundings, exactly as np
            unsigned long long key = ((unsigned long long)__float_as_uint(s) << 32)
                                   | (unsigned long long)(unsigned)n;
            atomicMin(&keys[m], key);
        }
    } else {
        // overflow fallback: exhaustive exact rescore (correctness insurance)
        for (int i = tid; i < MB * KCB; i += 256) {
            int m = i >> 12, n = i & 4095;
            const float4* er4 = (const float4*)(emb + (size_t)n * DDIM);
            const float4* zr4 = (const float4*)&zrow_s[m][0];
            float a = 0.f;
#pragma unroll
            for (int j4 = 0; j4 < 16; ++j4) {
                float4 ev = er4[j4];
                float4 zv = zr4[j4];
                a = fmaf(zv.x + zv.x, ev.x, a);
                a = fmaf(zv.y + zv.y, ev.y, a);
                a = fmaf(zv.z + zv.z, ev.z, a);
                a = fmaf(zv.w + zv.w, ev.w, a);
            }
            float s = (z2s[m] + e2g[n]) - a;
            unsigned long long key = ((unsigned long long)__float_as_uint(s) << 32)
                                   | (unsigned long long)(unsigned)n;
            atomicMin(&keys[m], key);
        }
    }
    __syncthreads();

    if (tid < MB) {
        int nstar = (int)(keys[tid] & 0xffffffffULL);
        bidx_s[tid] = nstar;
        out[IDXOFF + tok0 + tid] = (float)nstar;
    }
    __syncthreads();

    // ---- Epilogue: quantized gather-write (coalesced float4) + loss ----
    float* red = (float*)list;    // list is dead past the rescore barrier
    float lsum = 0.f;
#pragma unroll
    for (int it = 0; it < 4; ++it) {
        int f  = it * 256 + tid;    // 0..1023 float4 slots (64 tok * 16)
        int tt = f >> 4, cc = f & 15;
        int idx = bidx_s[tt];
        float4 qv = ((const float4*)(emb + (size_t)idx * DDIM))[cc];
        float4 zv = *(const float4*)&zrow_s[tt][cc * 4];
        ((float4*)(out + zbase))[f] = qv;
        float dx = qv.x - zv.x, dy = qv.y - zv.y;
        float dz = qv.z - zv.z, dw = qv.w - zv.w;
        lsum += dx * dx + dy * dy + dz * dz + dw * dw;
    }
    red[tid] = lsum;
    __syncthreads();
    for (int s = 128; s > 0; s >>= 1) {
        if (tid < s) red[tid] += red[tid + s];
        __syncthreads();
    }
    // ---- fused finalize: last block writes the loss (saves k_fin launch) ----
    if (tid == 0) {
        atomicAdd(lossacc, (double)red[0]);
        __threadfence();                       // order lossacc add before counter
        unsigned prev = atomicAdd(donecnt, 1u);
        if (prev == gridDim.x - 1) {
            __threadfence();                   // acquire: all adds visible
            out[LOSSOFF] = (float)(2.0 * (*lossacc) / (double)(NTOK * DDIM));
        }
    }
}

extern "C" void kernel_launch(void* const* d_in, const int* in_sizes, int n_in,
                              void* d_out, int out_size, void* d_ws, size_t ws_size,
                              hipStream_t stream) {
    const float* z   = (const float*)d_in[0];   // [16,4096,64] fp32
    const float* emb = (const float*)d_in[1];   // [4096,64] fp32
    float* out = (float*)d_out;

    char* ws = (char*)d_ws;
    float*    e2g     = (float*)(ws);                     // 16 KB
    uint4*    pfh     = (uint4*)(ws + 16384);             // 512 KB packed high frags
    double*   lossacc = (double*)(ws + 16384 + 524288);
    unsigned* donecnt = (unsigned*)(ws + 16384 + 524288 + 8);

    hipLaunchKernelGGL(k_prep, dim3(64), dim3(64), 0, stream, emb, e2g, pfh, lossacc, donecnt);
    hipLaunchKernelGGL(k_vq, dim3(NTOK / MB), dim3(256), 0, stream,
                       z, emb, e2g, pfh, out, lossacc, donecnt);
}

// Round 15
// 156.663 us; speedup vs baseline: 12.4134x; 12.4134x over previous
//
#include <hip/hip_runtime.h>

// Problem constants
#define NTOK 65536          // B*S tokens
#define DDIM 64             // embedding dim
#define KCB  4096           // codebook size
#define MB   64             // tokens per block
#define NTILES 256          // 16-col tiles in codebook
#define TPW  128            // tiles per wave (half codebook; 2 waves share a half)
#define LCAP 4096           // candidate capacity (~1300/block; exhaustive fallback on overflow)
#define WWIN 5.0e-4f        // >= 2*delta; delta <= 2.2e-4 (single-product worst case)
#define IDXOFF  (NTOK * DDIM)
#define LOSSOFF (NTOK * DDIM + NTOK)
#define ZPAD 68             // LDS row stride (floats): 272B, 16B-aligned, breaks banks

typedef __bf16 bf16x8 __attribute__((ext_vector_type(8)));
typedef float  f32x4  __attribute__((ext_vector_type(4)));

__device__ __forceinline__ float opaque(float x) { asm volatile("" : "+v"(x)); return x; }

// numpy pairwise sum of squares, n=64
__device__ __forceinline__ float np_sumsq64(const float* __restrict__ v) {
    float r[8];
#pragma unroll
    for (int j = 0; j < 8; ++j) r[j] = opaque(v[j] * v[j]);
#pragma unroll
    for (int i = 1; i < 8; ++i)
#pragma unroll
        for (int j = 0; j < 8; ++j) r[j] += opaque(v[8 * i + j] * v[8 * i + j]);
    return ((r[0] + r[1]) + (r[2] + r[3])) + ((r[4] + r[5]) + (r[6] + r[7]));
}

__device__ __forceinline__ unsigned short bf16rne(float x) {
    unsigned u = __float_as_uint(x);
    return (unsigned short)((u + 0x7fffu + ((u >> 16) & 1u)) >> 16);
}

// ---- Prep: exact e2 (np pairwise) + fragment-packed bf16(high) codebook ----
// pfh[tile*128 + kh*64 + lane]: lane = quad*16+l15 holds
//   bf16(e_row[tile*16+l15][quad*8 + kh*32 .. +8])  (16 B = 8 bf16)
__global__ void k_prep(const float* __restrict__ emb, float* __restrict__ e2,
                       uint4* __restrict__ pfh, double* __restrict__ lossacc) {
    int k = blockIdx.x * blockDim.x + threadIdx.x;
    if (k == 0) *lossacc = 0.0;
    if (k >= KCB) return;
    float row[DDIM];
    const float4* r4 = (const float4*)(emb + (size_t)k * DDIM);
#pragma unroll
    for (int i = 0; i < DDIM / 4; ++i) {
        float4 v = r4[i];
        row[4*i+0] = v.x; row[4*i+1] = v.y; row[4*i+2] = v.z; row[4*i+3] = v.w;
    }
    e2[k] = np_sumsq64(row);
    const int tile = k >> 4, rr = k & 15;
#pragma unroll
    for (int q = 0; q < 4; ++q) {
#pragma unroll
        for (int kh = 0; kh < 2; ++kh) {
            union { uint4 v; unsigned short s[8]; } th;
#pragma unroll
            for (int j = 0; j < 8; ++j) th.s[j] = bf16rne(row[q*8 + kh*32 + j]);
            pfh[(size_t)tile * 128 + kh * 64 + q * 16 + rr] = th.v;
        }
    }
}

// ---- Main: R8 EXACT REVERT — verified best (k_vq 99.6us, total 156.6us) ----
// 14-round ledger: every structural departure regressed — ballot/lane0
// capture (r9: 128us), loop re-skeleton (r10: 129us), thinner waves (r12:
// 167us), FIFO+fused-finalize (r14: 1883us, chip-wide residency collapse to
// 2% occupancy — suspected hidden scratch allocation throttling the grid).
// R8's components are each load-bearing: 256thr/4waves, wave (g,hh) = 32
// tokens x half codebook (VGPR 60 -> 3 waves/SIMD at the ~192-reg budget),
// unroll-1 conditional-prefetch skeleton, per-lane while(mask) capture with
// in-loop atomicAdd (latency hidden by 11 other waves/CU), fixed thr after
// 512-code preview seed, exact LDS rescore, separate k_fin.
// Exact rescore: s = fl(fl(z2+e2)-seqFMA(2z*e)) -> lex (s,n).
__global__ __launch_bounds__(256, 4)
void k_vq(const float* __restrict__ z, const float* __restrict__ emb,
          const float* __restrict__ e2g, const uint4* __restrict__ pfh,
          float* __restrict__ out, double* __restrict__ lossacc) {
    __shared__ float z2s[MB];
    __shared__ unsigned v0u[MB];
    __shared__ unsigned long long keys[MB];
    __shared__ unsigned list[LCAP];          // 16 KB; reused as red[] after rescore
    __shared__ int lcnt;
    __shared__ int bidx_s[MB];
    __shared__ float zrow_s[MB][ZPAD];       // 17 KB staged z block

    const int tid  = threadIdx.x;
    const int lane = tid & 63;
    const int l15  = lane & 15;
    const int quad = lane >> 4;
    const int wn   = tid >> 6;
    const int g    = wn >> 1;    // token half: tokens [g*32, g*32+32)
    const int hh   = wn & 1;     // tile half: tiles [hh*128, hh*128+128)
    const int tok0 = blockIdx.x * MB;
    const size_t zbase = (size_t)tok0 * DDIM;

    if (tid < MB) { v0u[tid] = 0x7f800000u; keys[tid] = 0xFFFFFFFFFFFFFFFFull; }
    if (tid == 0) lcnt = 0;

    // ---- A-fragments: bf16(-2z) for this wave's 32 tokens — 16 VGPRs ----
    bf16x8 Ah[2][2];   // [ms_local][kh]
#pragma unroll
    for (int ms = 0; ms < 2; ++ms) {
        const float* p = z + zbase + (size_t)((2 * g + ms) * 16 + l15) * DDIM + quad * 8;
#pragma unroll
        for (int kh = 0; kh < 2; ++kh) {
            float4 u0 = *(const float4*)(p + kh * 32);
            float4 u1 = *(const float4*)(p + kh * 32 + 4);
            float d[8] = {-(u0.x + u0.x), -(u0.y + u0.y), -(u0.z + u0.z), -(u0.w + u0.w),
                          -(u1.x + u1.x), -(u1.y + u1.y), -(u1.z + u1.z), -(u1.w + u1.w)};
            union { bf16x8 v; unsigned short u[8]; } th;
#pragma unroll
            for (int j = 0; j < 8; ++j) th.u[j] = bf16rne(d[j]);
            Ah[ms][kh] = th.v;
        }
    }

    // ---- Stage z block -> LDS (coalesced float4; rows padded to 68) ----
#pragma unroll
    for (int it = 0; it < 4; ++it) {
        int f = it * 256 + tid;              // 0..1023 float4 slots
        int tt = f >> 4, cc = f & 15;
        float4 v = ((const float4*)(z + zbase))[f];
        *(float4*)&zrow_s[tt][cc * 4] = v;
    }
    __syncthreads();   // zrow_s ready (also covers v0u/keys/lcnt init)

    // z2 per token (exact np pairwise) from LDS
    if (tid < MB) {
        float row[DDIM];
#pragma unroll
        for (int i = 0; i < DDIM / 4; ++i) {
            float4 v = *(const float4*)&zrow_s[tid][i * 4];
            row[4*i+0] = v.x; row[4*i+1] = v.y; row[4*i+2] = v.z; row[4*i+3] = v.w;
        }
        z2s[tid] = np_sumsq64(row);
    }

    const uint4* pbase = pfh + (size_t)hh * 128 * 128 + lane;

    // ---- preview (16 tiles/wave; 2 waves/token-half -> 512-code seed) ----
    float rm[8];
#pragma unroll
    for (int i = 0; i < 8; ++i) rm[i] = 3.0e38f;
#pragma unroll 1
    for (int t = 0; t < 16; ++t) {
        union { uint4 q; bf16x8 v; } b0, b1;
        b0.q = pbase[(size_t)t * 128]; b1.q = pbase[(size_t)t * 128 + 64];
#pragma unroll
        for (int ms = 0; ms < 2; ++ms) {
            f32x4 a = {0.5f, 0.5f, 0.5f, 0.5f};
            a = __builtin_amdgcn_mfma_f32_16x16x32_bf16(Ah[ms][0], b0.v, a, 0, 0, 0);
            a = __builtin_amdgcn_mfma_f32_16x16x32_bf16(Ah[ms][1], b1.v, a, 0, 0, 0);
#pragma unroll
            for (int r = 0; r < 4; ++r) rm[ms*4+r] = fminf(rm[ms*4+r], a[r]);
        }
    }
    // commit raw mins (16-lane group reduce -> block atomicMin)
#pragma unroll
    for (int i = 0; i < 8; ++i) {
        float v = rm[i];
        v = fminf(v, __shfl_xor(v, 1));
        v = fminf(v, __shfl_xor(v, 2));
        v = fminf(v, __shfl_xor(v, 4));
        v = fminf(v, __shfl_xor(v, 8));
        if (l15 == 0)
            atomicMin(&v0u[(2*g + (i>>2)) * 16 + quad*4 + (i&3)], __float_as_uint(v));
    }
    __syncthreads();   // v0u complete block-wide

    float thr[8];      // FIXED for the whole sweep: block 512-code min + W
#pragma unroll
    for (int i = 0; i < 8; ++i)
        thr[i] = __uint_as_float(v0u[(2*g + (i>>2)) * 16 + quad*4 + (i&3)]) + WWIN;

    // ---- main sweep: 2 tiles/iter, fixed thr, one branch region per pair ----
    auto compute2 = [&](uint4 p0, uint4 p1, uint4 q0, uint4 q1, int t) {
        unsigned mask = 0;
        {
            union { uint4 q; bf16x8 v; } b0, b1;
            b0.q = p0; b1.q = p1;
#pragma unroll
            for (int ms = 0; ms < 2; ++ms) {
                f32x4 a = {0.5f, 0.5f, 0.5f, 0.5f};
                a = __builtin_amdgcn_mfma_f32_16x16x32_bf16(Ah[ms][0], b0.v, a, 0, 0, 0);
                a = __builtin_amdgcn_mfma_f32_16x16x32_bf16(Ah[ms][1], b1.v, a, 0, 0, 0);
#pragma unroll
                for (int r = 0; r < 4; ++r)
                    mask |= (a[r] <= thr[ms*4+r]) ? (1u << (ms*4+r)) : 0u;
            }
        }
        {
            union { uint4 q; bf16x8 v; } b0, b1;
            b0.q = q0; b1.q = q1;
#pragma unroll
            for (int ms = 0; ms < 2; ++ms) {
                f32x4 a = {0.5f, 0.5f, 0.5f, 0.5f};
                a = __builtin_amdgcn_mfma_f32_16x16x32_bf16(Ah[ms][0], b0.v, a, 0, 0, 0);
                a = __builtin_amdgcn_mfma_f32_16x16x32_bf16(Ah[ms][1], b1.v, a, 0, 0, 0);
#pragma unroll
                for (int r = 0; r < 4; ++r)
                    mask |= (a[r] <= thr[ms*4+r]) ? (1u << (8 + ms*4+r)) : 0u;
            }
        }
        while (mask) {                        // exec-masked; skipped when empty
            int b = __builtin_ctz(mask);
            mask &= mask - 1;
            int ts = b >> 3, i = b & 7;
            int m = (2*g + (i >> 2)) * 16 + quad * 4 + (i & 3);
            int ncol = hh * 2048 + (t + ts) * 16 + l15;
            int idx = atomicAdd(&lcnt, 1);
            if (idx < LCAP)
                list[idx] = ((unsigned)m << 12) | (unsigned)ncol;
        }
    };

    uint4 a0 = pbase[0],   a1 = pbase[64];
    uint4 b0 = pbase[128], b1 = pbase[192];
    const uint4* pf = pbase + 256;
#pragma unroll 1
    for (int t = 0; t < TPW; t += 2) {
        uint4 c0 = a0, c1 = a1, d0 = b0, d1 = b1;
        if (t + 2 < TPW) {
            c0 = pf[0]; c1 = pf[64]; d0 = pf[128]; d1 = pf[192];
            pf += 256;
        }
        compute2(a0, a1, b0, b1, t);
        a0 = c0; a1 = c1; b0 = d0; b1 = d1;
    }
    __syncthreads();   // list complete & visible

    // ---- Exact rescore (np chain), lexicographic (s, n) min per token ----
    int cnt = lcnt;
    if (cnt <= LCAP) {
        for (int i = tid; i < cnt; i += 256) {
            unsigned e = list[i];
            int m = (int)(e >> 12), n = (int)(e & 4095u);
            const float4* er4 = (const float4*)(emb + (size_t)n * DDIM);
            const float4* zr4 = (const float4*)&zrow_s[m][0];
            float a = 0.f;
#pragma unroll
            for (int j4 = 0; j4 < 16; ++j4) {
                float4 ev = er4[j4];
                float4 zv = zr4[j4];
                a = fmaf(zv.x + zv.x, ev.x, a);
                a = fmaf(zv.y + zv.y, ev.y, a);
                a = fmaf(zv.z + zv.z, ev.z, a);
                a = fmaf(zv.w + zv.w, ev.w, a);
            }
            float s = (z2s[m] + e2g[n]) - a;   // two fp32 roundings, exactly as np
            unsigned long long key = ((unsigned long long)__float_as_uint(s) << 32)
                                   | (unsigned long long)(unsigned)n;
            atomicMin(&keys[m], key);
        }
    } else {
        // overflow fallback: exhaustive exact rescore (correctness insurance)
        for (int i = tid; i < MB * KCB; i += 256) {
            int m = i >> 12, n = i & 4095;
            const float4* er4 = (const float4*)(emb + (size_t)n * DDIM);
            const float4* zr4 = (const float4*)&zrow_s[m][0];
            float a = 0.f;
#pragma unroll
            for (int j4 = 0; j4 < 16; ++j4) {
                float4 ev = er4[j4];
                float4 zv = zr4[j4];
                a = fmaf(zv.x + zv.x, ev.x, a);
                a = fmaf(zv.y + zv.y, ev.y, a);
                a = fmaf(zv.z + zv.z, ev.z, a);
                a = fmaf(zv.w + zv.w, ev.w, a);
            }
            float s = (z2s[m] + e2g[n]) - a;
            unsigned long long key = ((unsigned long long)__float_as_uint(s) << 32)
                                   | (unsigned long long)(unsigned)n;
            atomicMin(&keys[m], key);
        }
    }
    __syncthreads();

    if (tid < MB) {
        int nstar = (int)(keys[tid] & 0xffffffffULL);
        bidx_s[tid] = nstar;
        out[IDXOFF + tok0 + tid] = (float)nstar;
    }
    __syncthreads();

    // ---- Epilogue: quantized gather-write (coalesced float4) + loss ----
    float* red = (float*)list;    // list is dead past the rescore barrier
    float lsum = 0.f;
#pragma unroll
    for (int it = 0; it < 4; ++it) {
        int f  = it * 256 + tid;    // 0..1023 float4 slots (64 tok * 16)
        int tt = f >> 4, cc = f & 15;
        int idx = bidx_s[tt];
        float4 qv = ((const float4*)(emb + (size_t)idx * DDIM))[cc];
        float4 zv = *(const float4*)&zrow_s[tt][cc * 4];
        ((float4*)(out + zbase))[f] = qv;
        float dx = qv.x - zv.x, dy = qv.y - zv.y;
        float dz = qv.z - zv.z, dw = qv.w - zv.w;
        lsum += dx * dx + dy * dy + dz * dz + dw * dw;
    }
    red[tid] = lsum;
    __syncthreads();
    for (int s = 128; s > 0; s >>= 1) {
        if (tid < s) red[tid] += red[tid + s];
        __syncthreads();
    }
    if (tid == 0) atomicAdd(lossacc, (double)red[0]);
}

__global__ void k_fin(const double* __restrict__ lossacc, float* __restrict__ out) {
    out[LOSSOFF] = (float)(2.0 * (*lossacc) / (double)(NTOK * DDIM));
}

extern "C" void kernel_launch(void* const* d_in, const int* in_sizes, int n_in,
                              void* d_out, int out_size, void* d_ws, size_t ws_size,
                              hipStream_t stream) {
    const float* z   = (const float*)d_in[0];   // [16,4096,64] fp32
    const float* emb = (const float*)d_in[1];   // [4096,64] fp32
    float* out = (float*)d_out;

    char* ws = (char*)d_ws;
    float*  e2g     = (float*)(ws);                 // 16 KB
    uint4*  pfh     = (uint4*)(ws + 16384);         // 512 KB packed high frags
    double* lossacc = (double*)(ws + 16384 + 524288);

    hipLaunchKernelGGL(k_prep, dim3(64), dim3(64), 0, stream, emb, e2g, pfh, lossacc);
    hipLaunchKernelGGL(k_vq, dim3(NTOK / MB), dim3(256), 0, stream,
                       z, emb, e2g, pfh, out, lossacc);
    hipLaunchKernelGGL(k_fin, dim3(1), dim3(1), 0, stream, lossacc, out);
}